// Round 5
// baseline (122.181 us; speedup 1.0000x reference)
//
#include <hip/hip_runtime.h>
#include <stdint.h>

#define NROW 16384
#define DDIM 128
#define ROWB 256            // bytes per row of bf16 z

constexpr int TS    = 256;                      // square tile side
constexpr int NTILE = NROW / TS;                // 64
constexpr int NBLK  = NTILE * (NTILE + 1) / 2;  // 2080 upper-tri tiles
constexpr int NB    = 64;                       // cols per j-tile
constexpr int JT    = TS / NB;                  // 4 j-tiles per block

typedef __bf16 bf16x8 __attribute__((ext_vector_type(8)));
typedef float  f32x4  __attribute__((ext_vector_type(4)));
typedef int    i32x4  __attribute__((ext_vector_type(4)));

__device__ __forceinline__ unsigned short f2bf(float x) {
  union { float f; uint32_t u; } c; c.f = x;
  uint32_t u = c.u + 0x7fffu + ((c.u >> 16) & 1u);   // RNE
  return (unsigned short)(u >> 16);
}

// fp32 -> bf16 with the scale folded in: (1/T) * sqrt(log2(e)),
// so the MFMA accumulator equals a*log2(e), ready for v_exp_f32 (exp2).
__global__ __launch_bounds__(256) void prep_kernel(const float* __restrict__ z,
                                                   unsigned short* __restrict__ zs,
                                                   float* __restrict__ s) {
  const float SC = 12.011224087864498f;  // 10 * sqrt(1.4426950408889634)
  int t = blockIdx.x * 256 + threadIdx.x;
  float4 v = reinterpret_cast<const float4*>(z)[t];
  ushort4 o;
  o.x = f2bf(v.x * SC); o.y = f2bf(v.y * SC);
  o.z = f2bf(v.z * SC); o.w = f2bf(v.w * SC);
  reinterpret_cast<ushort4*>(zs)[t] = o;
  if (t < NROW) s[t] = 0.0f;             // rowsum accumulator (ws is poisoned)
}

// Upper-triangle 256x256 tiles: block (bi,bj), bi<=bj. Off-diagonal tiles add
// rowsums to rows of tile bi AND colsums (== transposed rowsums, by symmetry
// of exp(zs zs^T)) to rows of tile bj. Diagonal: full tile, rowsums only.
//
// Round-4 lesson: zs is 4 MB == one XCD's L2. LDS-staging L2-resident data
// (Common-mistake #7) bought two barriers + vmcnt drains + bank conflicts per
// tile and left every pipe <30% busy. This version loads B fragments straight
// from L2, runs waves barrier-free, and uses LDS only for a 4 KB colsum slab.
// Round-2/3 lessons kept: no forced occupancy, jt loop stays ROLLED.
__global__ __launch_bounds__(256, 2) void gemm_exp_kernel(const unsigned short* __restrict__ zs,
                                                          float* __restrict__ s) {
  __shared__ __align__(16) float csm[4 * 256];   // [4 waves][256 cols]
  const int tid  = threadIdx.x;
  const int lane = tid & 63;
  const int wid  = tid >> 6;

  // linear block id -> (bi, bj) upper triangle, cum(i) = 64i - i(i-1)/2
  const int t = blockIdx.x;
#define CUM(i) (64 * (i) - ((i) * ((i) - 1)) / 2)
  int bi = (int)((129.0f - sqrtf((float)(16641 - 8 * t))) * 0.5f);
  while (CUM(bi + 1) <= t) ++bi;
  while (CUM(bi) > t) --bi;
  const int bj = bi + (t - CUM(bi));
  const bool isDiag = (bi == bj);
#undef CUM

  const int rowBase = bi * TS + wid * 64;   // this wave's 64 rows
  const int colBase = bj * TS;
  const char* zb = (const char*)zs;
  const int kb = (lane >> 4) << 4;          // 16B chunk within the K row

  // A fragments: 16x16x32 A layout row=lane&15, k=(lane>>4)*8+e -> 16B/lane.
  // Loaded once, reused for all 4 j-tiles.
  bf16x8 afrag[4][4];   // [mf][ks]
  {
    const int r0 = rowBase + (lane & 15);
#pragma unroll
    for (int mf = 0; mf < 4; ++mf)
#pragma unroll
      for (int ks = 0; ks < 4; ++ks) {
        i32x4 raw = *reinterpret_cast<const i32x4*>(
            zb + (size_t)(r0 + mf * 16) * ROWB + ks * 64 + kb);
        afrag[mf][ks] = __builtin_bit_cast(bf16x8, raw);
      }
  }

  float rs[4][4];   // rowsum accumulators
  float cs[4];      // colsum accumulators [nf], flushed to LDS each j-tile
#pragma unroll
  for (int mf = 0; mf < 4; ++mf)
#pragma unroll
    for (int r = 0; r < 4; ++r) rs[mf][r] = 0.0f;
#pragma unroll
  for (int nf = 0; nf < 4; ++nf) cs[nf] = 0.0f;

#pragma unroll 1   // KEEP ROLLED: jt-level unroll spills (round-3 post-mortem)
  for (int jt = 0; jt < JT; ++jt) {
    f32x4 acc[4][4];
#pragma unroll
    for (int mf = 0; mf < 4; ++mf)
#pragma unroll
      for (int nf = 0; nf < 4; ++nf) {
        f32x4 zv = {0.f, 0.f, 0.f, 0.f};
        acc[mf][nf] = zv;
      }

    // B fragments straight from L2 (same lane layout as A). 16 independent
    // 16B loads per ks-group; no barrier, no LDS round-trip.
    const int brow0 = colBase + jt * NB + (lane & 15);
#pragma unroll
    for (int ks = 0; ks < 4; ++ks) {
      bf16x8 bfrag[4];
#pragma unroll
      for (int nf = 0; nf < 4; ++nf) {
        i32x4 raw = *reinterpret_cast<const i32x4*>(
            zb + (size_t)(brow0 + nf * 16) * ROWB + ks * 64 + kb);
        bfrag[nf] = __builtin_bit_cast(bf16x8, raw);
      }
#pragma unroll
      for (int mf = 0; mf < 4; ++mf)
#pragma unroll
        for (int nf = 0; nf < 4; ++nf)
          acc[mf][nf] = __builtin_amdgcn_mfma_f32_16x16x32_bf16(
              afrag[mf][ks], bfrag[nf], acc[mf][nf], 0, 0, 0);
    }

    // acc holds a*log2(e) -> exp(a) = exp2(acc); feed row + col accumulators
#pragma unroll
    for (int mf = 0; mf < 4; ++mf)
#pragma unroll
      for (int nf = 0; nf < 4; ++nf) {
        f32x4 a4 = acc[mf][nf];
        float e0 = __builtin_amdgcn_exp2f(a4[0]);
        float e1 = __builtin_amdgcn_exp2f(a4[1]);
        float e2 = __builtin_amdgcn_exp2f(a4[2]);
        float e3 = __builtin_amdgcn_exp2f(a4[3]);
        rs[mf][0] += e0; rs[mf][1] += e1; rs[mf][2] += e2; rs[mf][3] += e3;
        cs[nf] += (e0 + e1) + (e2 + e3);
      }

    // Flush colsum partials for this j-tile: reduce the 4 hi-groups, park in
    // csm (per-wave slice, no cross-wave race), free the registers.
#pragma unroll
    for (int nf = 0; nf < 4; ++nf) {
      float v = cs[nf];
      v += __shfl_xor(v, 16);
      v += __shfl_xor(v, 32);
      if (lane < 16) csm[wid * 256 + jt * 64 + nf * 16 + lane] = v;
      cs[nf] = 0.0f;
    }
  }

  // Rowsums: C/D layout col=lane&15, row=(lane>>4)*4+reg. Reduce the 16
  // column-lanes, one atomicAdd per row.
#pragma unroll
  for (int mf = 0; mf < 4; ++mf)
#pragma unroll
    for (int r = 0; r < 4; ++r) {
      float v = rs[mf][r];
      v += __shfl_xor(v, 1);
      v += __shfl_xor(v, 2);
      v += __shfl_xor(v, 4);
      v += __shfl_xor(v, 8);
      if ((lane & 15) == 0) {
        const int row = rowBase + mf * 16 + ((lane >> 4) << 2) + r;
        atomicAdd(&s[row], v);
      }
    }

  // Colsums (off-diagonal only): combine the 4 per-wave slabs, one atomic
  // per column. __syncthreads drains the csm ds_writes.
  if (!isDiag) {
    __syncthreads();
    float sum = csm[tid] + csm[256 + tid] + csm[512 + tid] + csm[768 + tid];
    atomicAdd(&s[colBase + tid], sum);
  }
}

__global__ __launch_bounds__(1024) void reduce_kernel(const float* __restrict__ s,
                                                      float* __restrict__ out) {
  const int tid = threadIdx.x;
  float acc = 0.0f;
  for (int i = tid; i < NROW; i += 1024) acc += __log2f(s[i]);
#pragma unroll
  for (int m = 32; m >= 1; m >>= 1) acc += __shfl_xor(acc, m);
  __shared__ float wsum[16];
  if ((tid & 63) == 0) wsum[tid >> 6] = acc;
  __syncthreads();
  if (tid == 0) {
    float tot = 0.0f;
#pragma unroll
    for (int w = 0; w < 16; ++w) tot += wsum[w];
    // mean(-log(sum/N)) = log N - (ln2/N) * sum(log2 s_i)
    out[0] = logf((float)NROW) - 0.6931471805599453f * tot / (float)NROW;
  }
}

extern "C" void kernel_launch(void* const* d_in, const int* in_sizes, int n_in,
                              void* d_out, int out_size, void* d_ws, size_t ws_size,
                              hipStream_t stream) {
  const float* z = (const float*)d_in[0];
  unsigned short* zs = (unsigned short*)d_ws;                       // 4 MB bf16
  float* s = (float*)((char*)d_ws + (size_t)NROW * DDIM * 2);       // 64 KB rowsums
  float* out = (float*)d_out;

  prep_kernel<<<dim3(NROW * DDIM / 4 / 256), dim3(256), 0, stream>>>(z, zs, s);
  gemm_exp_kernel<<<dim3(NBLK), dim3(256), 0, stream>>>(zs, s);
  reduce_kernel<<<dim3(1), dim3(1024), 0, stream>>>(s, out);
}

// Round 6
// 79.928 us; speedup vs baseline: 1.5286x; 1.5286x over previous
//
#include <hip/hip_runtime.h>
#include <stdint.h>

#define NROW 16384
#define DDIM 128
#define ROWB 256            // bytes per row of bf16 z

constexpr int NB     = 64;              // cols per j-tile
constexpr int NJT    = NROW / NB;       // 256 j-tiles across the matrix
constexpr int CHUNK  = 16;              // max j-tiles per block
constexpr int NSTRIP = 64;              // row strips of 256
// blocks = sum_I ceil((256-4I)/16) = 544
constexpr int NBLK   = 544;

typedef __bf16 bf16x8 __attribute__((ext_vector_type(8)));
typedef float  f32x4  __attribute__((ext_vector_type(4)));
typedef int    i32x4  __attribute__((ext_vector_type(4)));

typedef const uint32_t __attribute__((address_space(1)))* gptr_t;
typedef uint32_t __attribute__((address_space(3)))*       lptr_t;

__device__ __forceinline__ unsigned short f2bf(float x) {
  union { float f; uint32_t u; } c; c.f = x;
  uint32_t u = c.u + 0x7fffu + ((c.u >> 16) & 1u);   // RNE
  return (unsigned short)(u >> 16);
}

// fp32 -> bf16 with the scale folded in: (1/T) * sqrt(log2(e)),
// so the MFMA accumulator equals a*log2(e), ready for v_exp_f32 (exp2).
__global__ __launch_bounds__(256) void prep_kernel(const float* __restrict__ z,
                                                   unsigned short* __restrict__ zs,
                                                   float* __restrict__ s) {
  const float SC = 12.011224087864498f;  // 10 * sqrt(1.4426950408889634)
  int t = blockIdx.x * 256 + threadIdx.x;
  float4 v = reinterpret_cast<const float4*>(z)[t];
  ushort4 o;
  o.x = f2bf(v.x * SC); o.y = f2bf(v.y * SC);
  o.z = f2bf(v.z * SC); o.w = f2bf(v.w * SC);
  reinterpret_cast<ushort4*>(zs)[t] = o;
  if (t < NROW) s[t] = 0.0f;             // rowsum accumulator (ws is poisoned)
}

// Symmetry via row-strips: strip I (rows [256I,256I+256)) computes j-tiles
// with col >= 256I only. Off-diagonal-block tiles also contribute colsums
// (= transposed rowsums, since exp(zs zs^T) is symmetric). Each strip's run
// of (256-4I) j-tiles is cut into chunks of <=16 -> long staging pipeline
// (round-4 lesson: JT=4 left the machine in prologue/epilogue half the time;
// round-5 lesson: keep LDS staging, it hides L2 latency at low occupancy;
// rounds-2/3 lessons: no forced occupancy cap, keep the jt loop ROLLED).
__global__ __launch_bounds__(256, 2) void gemm_exp_kernel(const unsigned short* __restrict__ zs,
                                                          float* __restrict__ s) {
  __shared__ __align__(16) char smem[2 * NB * ROWB + 4 * CHUNK * 64 * 4]; // 32K dbuf + 16K csm
  float* csm = (float*)(smem + 2 * NB * ROWB);   // [4 waves][CHUNK*64 cols]
  const int tid  = threadIdx.x;
  const int lane = tid & 63;
  const int wid  = tid >> 6;

  // blockIdx.x -> (strip I, chunk c) over variable-length strips
  int I = 0, c = 0;
  {
    const int bid = blockIdx.x;
    int a = 0;
    for (int i = 0; i < NSTRIP; ++i) {
      const int n = (NSTRIP - i + 3) >> 2;       // ceil((64-i)/4) blocks in strip
      if (bid < a + n) { I = i; c = bid - a; break; }
      a += n;
    }
  }
  const int mI     = NJT - 4 * I;                // j-tiles in this strip
  const int jt0    = 4 * I + CHUNK * c;          // first global j-tile
  const int JT_blk = min(CHUNK, mI - CHUNK * c); // tiles this block runs

  const int rowBase = I * 256 + wid * 64;        // this wave's 64 rows
  const char* zb = (const char*)zs;
  const int kb = (lane >> 4) << 4;               // 16B chunk within K row

  // A fragments: 16x16x32 A layout row=lane&15, k=(lane>>4)*8+e -> 16B/lane
  bf16x8 afrag[4][4];   // [mf][ks]
  {
    const int r0 = rowBase + (lane & 15);
#pragma unroll
    for (int mf = 0; mf < 4; ++mf)
#pragma unroll
      for (int ks = 0; ks < 4; ++ks) {
        i32x4 raw = *reinterpret_cast<const i32x4*>(
            zb + (size_t)(r0 + mf * 16) * ROWB + ks * 64 + kb);
        afrag[mf][ks] = __builtin_bit_cast(bf16x8, raw);
      }
  }

  float rs[4][4];   // rowsum accumulators
  float cs[4];      // colsum accumulators [nf], flushed to LDS each j-tile
#pragma unroll
  for (int mf = 0; mf < 4; ++mf)
#pragma unroll
    for (int r = 0; r < 4; ++r) rs[mf][r] = 0.0f;
#pragma unroll
  for (int nf = 0; nf < 4; ++nf) cs[nf] = 0.0f;

  // Stage j-tile (jt0+k): 64 zs-rows starting at (jt0+k)*64. Linear LDS dest
  // + inverse-XOR-swizzled global source; reads apply the same involution.
#define STAGE_B(buf, k)                                                          \
  {                                                                              \
    _Pragma("unroll")                                                            \
    for (int i_ = 0; i_ < 4; ++i_) {                                             \
      const int destByte_ = wid * 4096 + i_ * 1024 + lane * 16;                  \
      const int r_  = destByte_ >> 8;                                            \
      const int cb_ = destByte_ & 0xF0;                                          \
      const int srcByte_ = ((jt0 + (k)) * NB + r_) * ROWB                        \
                           + (cb_ ^ ((r_ & 7) << 4));                            \
      __builtin_amdgcn_global_load_lds((gptr_t)(zb + srcByte_),                  \
          (lptr_t)(smem + (buf) * (NB * ROWB) + destByte_), 16, 0, 0);           \
    }                                                                            \
  }

  STAGE_B(0, 0);

#pragma unroll 1   // KEEP ROLLED: unrolling pipelines iterations and spills
  for (int k = 0; k < JT_blk; ++k) {
    const int cur = k & 1;
    if (k + 1 < JT_blk) {
      STAGE_B(cur ^ 1, k + 1);
      asm volatile("s_waitcnt vmcnt(4)" ::: "memory");  // current tile landed
    } else {
      asm volatile("s_waitcnt vmcnt(0)" ::: "memory");
    }
    __builtin_amdgcn_s_barrier();

    f32x4 acc[4][4];
#pragma unroll
    for (int mf = 0; mf < 4; ++mf)
#pragma unroll
      for (int nf = 0; nf < 4; ++nf) {
        f32x4 zv = {0.f, 0.f, 0.f, 0.f};
        acc[mf][nf] = zv;
      }

    const char* bufp = smem + cur * (NB * ROWB);
#pragma unroll
    for (int ks = 0; ks < 4; ++ks) {
      bf16x8 bfrag[4];
#pragma unroll
      for (int nf = 0; nf < 4; ++nf) {
        const int r   = nf * 16 + (lane & 15);
        const int kk  = ks * 64 + kb;
        const int off = r * ROWB + (kk ^ ((r & 7) << 4));
        i32x4 raw = *reinterpret_cast<const i32x4*>(bufp + off);
        bfrag[nf] = __builtin_bit_cast(bf16x8, raw);
      }
#pragma unroll
      for (int mf = 0; mf < 4; ++mf)
#pragma unroll
        for (int nf = 0; nf < 4; ++nf)
          acc[mf][nf] = __builtin_amdgcn_mfma_f32_16x16x32_bf16(
              afrag[mf][ks], bfrag[nf], acc[mf][nf], 0, 0, 0);
    }

    // acc holds a*log2(e) -> exp(a) = exp2(acc); feed row + col accumulators
#pragma unroll
    for (int mf = 0; mf < 4; ++mf)
#pragma unroll
      for (int nf = 0; nf < 4; ++nf) {
        f32x4 a4 = acc[mf][nf];
        float e0 = __builtin_amdgcn_exp2f(a4[0]);
        float e1 = __builtin_amdgcn_exp2f(a4[1]);
        float e2 = __builtin_amdgcn_exp2f(a4[2]);
        float e3 = __builtin_amdgcn_exp2f(a4[3]);
        rs[mf][0] += e0; rs[mf][1] += e1; rs[mf][2] += e2; rs[mf][3] += e3;
        cs[nf] += (e0 + e1) + (e2 + e3);
      }

    // Flush colsum partials for this tile into the per-wave LDS slab.
#pragma unroll
    for (int nf = 0; nf < 4; ++nf) {
      float v = cs[nf];
      v += __shfl_xor(v, 16);
      v += __shfl_xor(v, 32);
      if (lane < 16) csm[wid * (CHUNK * 64) + k * 64 + nf * 16 + lane] = v;
      cs[nf] = 0.0f;
    }

    __builtin_amdgcn_s_barrier();   // all waves done reading buf[cur]
  }
#undef STAGE_B

  // Rowsums: C/D layout col=lane&15, row=(lane>>4)*4+reg. Reduce the 16
  // column-lanes, one atomicAdd per row.
#pragma unroll
  for (int mf = 0; mf < 4; ++mf)
#pragma unroll
    for (int r = 0; r < 4; ++r) {
      float v = rs[mf][r];
      v += __shfl_xor(v, 1);
      v += __shfl_xor(v, 2);
      v += __shfl_xor(v, 4);
      v += __shfl_xor(v, 8);
      if ((lane & 15) == 0) {
        const int row = rowBase + mf * 16 + ((lane >> 4) << 2) + r;
        atomicAdd(&s[row], v);
      }
    }

  // Colsums: combine the 4 per-wave slabs, one atomic per column. Skip
  // columns inside this strip's diagonal 256-block (computed fully there).
  __syncthreads();   // drain csm ds_writes across waves
  {
    const int colBase0 = jt0 * NB;
    const int diagEnd  = (I + 1) * 256;
    const int ncol     = JT_blk * NB;
#pragma unroll
    for (int k4 = 0; k4 < 4; ++k4) {
      const int idx = k4 * 256 + tid;
      if (idx < ncol) {
        const int col = colBase0 + idx;
        if (col >= diagEnd) {
          float sum = csm[idx] + csm[CHUNK * 64 + idx]
                    + csm[2 * CHUNK * 64 + idx] + csm[3 * CHUNK * 64 + idx];
          atomicAdd(&s[col], sum);
        }
      }
    }
  }
}

__global__ __launch_bounds__(1024) void reduce_kernel(const float* __restrict__ s,
                                                      float* __restrict__ out) {
  const int tid = threadIdx.x;
  float acc = 0.0f;
  for (int i = tid; i < NROW; i += 1024) acc += __log2f(s[i]);
#pragma unroll
  for (int m = 32; m >= 1; m >>= 1) acc += __shfl_xor(acc, m);
  __shared__ float wsum[16];
  if ((tid & 63) == 0) wsum[tid >> 6] = acc;
  __syncthreads();
  if (tid == 0) {
    float tot = 0.0f;
#pragma unroll
    for (int w = 0; w < 16; ++w) tot += wsum[w];
    // mean(-log(sum/N)) = log N - (ln2/N) * sum(log2 s_i)
    out[0] = logf((float)NROW) - 0.6931471805599453f * tot / (float)NROW;
  }
}

extern "C" void kernel_launch(void* const* d_in, const int* in_sizes, int n_in,
                              void* d_out, int out_size, void* d_ws, size_t ws_size,
                              hipStream_t stream) {
  const float* z = (const float*)d_in[0];
  unsigned short* zs = (unsigned short*)d_ws;                       // 4 MB bf16
  float* s = (float*)((char*)d_ws + (size_t)NROW * DDIM * 2);       // 64 KB rowsums
  float* out = (float*)d_out;

  prep_kernel<<<dim3(NROW * DDIM / 4 / 256), dim3(256), 0, stream>>>(z, zs, s);
  gemm_exp_kernel<<<dim3(NBLK), dim3(256), 0, stream>>>(zs, s);
  reduce_kernel<<<dim3(1), dim3(1024), 0, stream>>>(s, out);
}

// Round 7
// 66.964 us; speedup vs baseline: 1.8246x; 1.1936x over previous
//
#include <hip/hip_runtime.h>
#include <stdint.h>

#define NROW 16384
#define DDIM 128
#define ROWB 256            // bytes per row of bf16 z

constexpr int NB     = 64;              // cols per j-tile
constexpr int NJT    = NROW / NB;       // 256 j-tiles across the matrix
constexpr int CHUNK  = 8;               // max j-tiles per block
constexpr int NSTRIP = 128;             // row strips of 128
// strip I has ceil((256-2I)/8) = ceil((128-I)/4) blocks; total = S(128) = 2112
constexpr int NBLK   = 2112;

typedef __bf16 bf16x8 __attribute__((ext_vector_type(8)));
typedef float  f32x4  __attribute__((ext_vector_type(4)));
typedef int    i32x4  __attribute__((ext_vector_type(4)));

typedef const uint32_t __attribute__((address_space(1)))* gptr_t;
typedef uint32_t __attribute__((address_space(3)))*       lptr_t;

__device__ __forceinline__ unsigned short f2bf(float x) {
  union { float f; uint32_t u; } c; c.f = x;
  uint32_t u = c.u + 0x7fffu + ((c.u >> 16) & 1u);   // RNE
  return (unsigned short)(u >> 16);
}

// S(k) = sum_{x=1..k} ceil(x/4)  (blocks in the last k strips)
__device__ __forceinline__ int Sfun(int k) {
  const int q = k >> 2, r = k & 3;
  return 2 * q * (q + 1) + r * (q + 1);
}

// fp32 -> bf16 with the scale folded in: (1/T) * sqrt(log2(e)),
// so the MFMA accumulator equals a*log2(e), ready for v_exp_f32 (exp2).
__global__ __launch_bounds__(256) void prep_kernel(const float* __restrict__ z,
                                                   unsigned short* __restrict__ zs,
                                                   float* __restrict__ s) {
  const float SC = 12.011224087864498f;  // 10 * sqrt(1.4426950408889634)
  int t = blockIdx.x * 256 + threadIdx.x;
  float4 v = reinterpret_cast<const float4*>(z)[t];
  ushort4 o;
  o.x = f2bf(v.x * SC); o.y = f2bf(v.y * SC);
  o.z = f2bf(v.z * SC); o.w = f2bf(v.w * SC);
  reinterpret_cast<ushort4*>(zs)[t] = o;
  if (t < NROW) s[t] = 0.0f;             // rowsum accumulator (ws is poisoned)
}

// Symmetry via 128-row strips: strip I (rows [128I,128I+128)) computes j-tiles
// j >= 2I (cols >= 128I). Tiles with cols >= 128(I+1) also contribute colsums
// (= transposed rowsums of the symmetric exp matrix); the two tiles covering
// the diagonal 128x128 square are rowsum-only (square is its own transpose).
//
// Round-7 change: wave owns 32 rows (mf=2), halving acc (64->32 AGPR) and
// afrag (32->16 VGPR). Rounds 1/4/6 all pinned at ~170 regs/wave -> 2-3
// waves/SIMD regardless of grid/LDS; that register cap, not pipeline depth,
// was the stall-fill limit. LDS trimmed to 40 KB = exactly 4 blocks/CU.
// Kept lessons: LDS staging (r5), rolled jt loop (r3), no forced bounds (r2).
__global__ __launch_bounds__(256, 2) void gemm_exp_kernel(const unsigned short* __restrict__ zs,
                                                          float* __restrict__ s) {
  __shared__ __align__(16) char smem[2 * NB * ROWB + 4 * CHUNK * 64 * 4]; // 32K dbuf + 8K csm
  float* csm = (float*)(smem + 2 * NB * ROWB);   // [4 waves][CHUNK*64 cols]
  const int tid  = threadIdx.x;
  const int lane = tid & 63;
  const int wid  = tid >> 6;

  // blockIdx.x -> (strip I, chunk c): smallest k with S(k) >= NBLK - bid,
  // then I = 128-k, block offset = bid - (NBLK - S(k)).
  int I, c;
  {
    const int bid = blockIdx.x;
    const int m = NBLK - bid;
    int k = (int)sqrtf(8.0f * (float)m);
    if (k > 128) k = 128;
    while (Sfun(k) < m) ++k;
    while (k > 1 && Sfun(k - 1) >= m) --k;
    I = 128 - k;
    c = bid - (NBLK - Sfun(k));
  }
  const int mI     = NJT - 2 * I;                // j-tiles in this strip
  const int jt0    = 2 * I + CHUNK * c;          // first global j-tile
  const int JT_blk = min(CHUNK, mI - CHUNK * c); // tiles this block runs

  const int rowBase = I * 128 + wid * 32;        // this wave's 32 rows
  const char* zb = (const char*)zs;
  const int kb = (lane >> 4) << 4;               // 16B chunk within K row

  // A fragments: 16x16x32 A layout row=lane&15, k=(lane>>4)*8+e -> 16B/lane
  bf16x8 afrag[2][4];   // [mf][ks]
  {
    const int r0 = rowBase + (lane & 15);
#pragma unroll
    for (int mf = 0; mf < 2; ++mf)
#pragma unroll
      for (int ks = 0; ks < 4; ++ks) {
        i32x4 raw = *reinterpret_cast<const i32x4*>(
            zb + (size_t)(r0 + mf * 16) * ROWB + ks * 64 + kb);
        afrag[mf][ks] = __builtin_bit_cast(bf16x8, raw);
      }
  }

  float rs[2][4];   // rowsum accumulators
  float cs[4];      // colsum accumulators [nf], flushed to LDS each j-tile
#pragma unroll
  for (int mf = 0; mf < 2; ++mf)
#pragma unroll
    for (int r = 0; r < 4; ++r) rs[mf][r] = 0.0f;
#pragma unroll
  for (int nf = 0; nf < 4; ++nf) cs[nf] = 0.0f;

  // Stage j-tile (jt0+k): 64 zs-rows starting at (jt0+k)*64. Linear LDS dest
  // + inverse-XOR-swizzled global source; reads apply the same involution.
#define STAGE_B(buf, k)                                                          \
  {                                                                              \
    _Pragma("unroll")                                                            \
    for (int i_ = 0; i_ < 4; ++i_) {                                             \
      const int destByte_ = wid * 4096 + i_ * 1024 + lane * 16;                  \
      const int r_  = destByte_ >> 8;                                            \
      const int cb_ = destByte_ & 0xF0;                                          \
      const int srcByte_ = ((jt0 + (k)) * NB + r_) * ROWB                        \
                           + (cb_ ^ ((r_ & 7) << 4));                            \
      __builtin_amdgcn_global_load_lds((gptr_t)(zb + srcByte_),                  \
          (lptr_t)(smem + (buf) * (NB * ROWB) + destByte_), 16, 0, 0);           \
    }                                                                            \
  }

  STAGE_B(0, 0);

#pragma unroll 1   // KEEP ROLLED: unrolling pipelines iterations and spills
  for (int k = 0; k < JT_blk; ++k) {
    const int cur = k & 1;
    if (k + 1 < JT_blk) {
      STAGE_B(cur ^ 1, k + 1);
      asm volatile("s_waitcnt vmcnt(4)" ::: "memory");  // current tile landed
    } else {
      asm volatile("s_waitcnt vmcnt(0)" ::: "memory");
    }
    __builtin_amdgcn_s_barrier();

    f32x4 acc[2][4];
#pragma unroll
    for (int mf = 0; mf < 2; ++mf)
#pragma unroll
      for (int nf = 0; nf < 4; ++nf) {
        f32x4 zv = {0.f, 0.f, 0.f, 0.f};
        acc[mf][nf] = zv;
      }

    const char* bufp = smem + cur * (NB * ROWB);
#pragma unroll
    for (int ks = 0; ks < 4; ++ks) {
      bf16x8 bfrag[4];
#pragma unroll
      for (int nf = 0; nf < 4; ++nf) {
        const int r   = nf * 16 + (lane & 15);
        const int kk  = ks * 64 + kb;
        const int off = r * ROWB + (kk ^ ((r & 7) << 4));
        i32x4 raw = *reinterpret_cast<const i32x4*>(bufp + off);
        bfrag[nf] = __builtin_bit_cast(bf16x8, raw);
      }
#pragma unroll
      for (int mf = 0; mf < 2; ++mf)
#pragma unroll
        for (int nf = 0; nf < 4; ++nf)
          acc[mf][nf] = __builtin_amdgcn_mfma_f32_16x16x32_bf16(
              afrag[mf][ks], bfrag[nf], acc[mf][nf], 0, 0, 0);
    }

    // acc holds a*log2(e) -> exp(a) = exp2(acc); feed row + col accumulators
#pragma unroll
    for (int mf = 0; mf < 2; ++mf)
#pragma unroll
      for (int nf = 0; nf < 4; ++nf) {
        f32x4 a4 = acc[mf][nf];
        float e0 = __builtin_amdgcn_exp2f(a4[0]);
        float e1 = __builtin_amdgcn_exp2f(a4[1]);
        float e2 = __builtin_amdgcn_exp2f(a4[2]);
        float e3 = __builtin_amdgcn_exp2f(a4[3]);
        rs[mf][0] += e0; rs[mf][1] += e1; rs[mf][2] += e2; rs[mf][3] += e3;
        cs[nf] += (e0 + e1) + (e2 + e3);
      }

    // Flush colsum partials for this tile into the per-wave LDS slab.
#pragma unroll
    for (int nf = 0; nf < 4; ++nf) {
      float v = cs[nf];
      v += __shfl_xor(v, 16);
      v += __shfl_xor(v, 32);
      if (lane < 16) csm[wid * (CHUNK * 64) + k * 64 + nf * 16 + lane] = v;
      cs[nf] = 0.0f;
    }

    __builtin_amdgcn_s_barrier();   // all waves done reading buf[cur]
  }
#undef STAGE_B

  // Rowsums: C/D layout col=lane&15, row=(lane>>4)*4+reg. Reduce the 16
  // column-lanes, one atomicAdd per row.
#pragma unroll
  for (int mf = 0; mf < 2; ++mf)
#pragma unroll
    for (int r = 0; r < 4; ++r) {
      float v = rs[mf][r];
      v += __shfl_xor(v, 1);
      v += __shfl_xor(v, 2);
      v += __shfl_xor(v, 4);
      v += __shfl_xor(v, 8);
      if ((lane & 15) == 0) {
        const int row = rowBase + mf * 16 + ((lane >> 4) << 2) + r;
        atomicAdd(&s[row], v);
      }
    }

  // Colsums: combine the 4 per-wave slabs, one atomic per column. Skip
  // columns inside this strip's diagonal 128-block (computed fully there).
  __syncthreads();   // drain csm ds_writes across waves
  {
    const int colBase0 = jt0 * NB;
    const int diagEnd  = (I + 1) * 128;
    const int ncol     = JT_blk * NB;
#pragma unroll
    for (int k4 = 0; k4 < 2; ++k4) {
      const int idx = k4 * 256 + tid;
      if (idx < ncol) {
        const int col = colBase0 + idx;
        if (col >= diagEnd) {
          float sum = csm[idx] + csm[CHUNK * 64 + idx]
                    + csm[2 * CHUNK * 64 + idx] + csm[3 * CHUNK * 64 + idx];
          atomicAdd(&s[col], sum);
        }
      }
    }
  }
}

__global__ __launch_bounds__(1024) void reduce_kernel(const float* __restrict__ s,
                                                      float* __restrict__ out) {
  const int tid = threadIdx.x;
  float acc = 0.0f;
  for (int i = tid; i < NROW; i += 1024) acc += __log2f(s[i]);
#pragma unroll
  for (int m = 32; m >= 1; m >>= 1) acc += __shfl_xor(acc, m);
  __shared__ float wsum[16];
  if ((tid & 63) == 0) wsum[tid >> 6] = acc;
  __syncthreads();
  if (tid == 0) {
    float tot = 0.0f;
#pragma unroll
    for (int w = 0; w < 16; ++w) tot += wsum[w];
    // mean(-log(sum/N)) = log N - (ln2/N) * sum(log2 s_i)
    out[0] = logf((float)NROW) - 0.6931471805599453f * tot / (float)NROW;
  }
}

extern "C" void kernel_launch(void* const* d_in, const int* in_sizes, int n_in,
                              void* d_out, int out_size, void* d_ws, size_t ws_size,
                              hipStream_t stream) {
  const float* z = (const float*)d_in[0];
  unsigned short* zs = (unsigned short*)d_ws;                       // 4 MB bf16
  float* s = (float*)((char*)d_ws + (size_t)NROW * DDIM * 2);       // 64 KB rowsums
  float* out = (float*)d_out;

  prep_kernel<<<dim3(NROW * DDIM / 4 / 256), dim3(256), 0, stream>>>(z, zs, s);
  gemm_exp_kernel<<<dim3(NBLK), dim3(256), 0, stream>>>(zs, s);
  reduce_kernel<<<dim3(1), dim3(1024), 0, stream>>>(s, out);
}